// Round 6
// baseline (180.639 us; speedup 1.0000x reference)
//
#include <hip/hip_runtime.h>
#include <math.h>

// FFF fused forward v5 — full 21-node speculation with NAMED SCALAR logits
// (r0..r20, macro-generated): arrays rA[21]/rB[21] were being demoted to
// scratch (R2/R4/R5: WRITE_SIZE ~195MB vs 50MB ideal, VGPR stuck at 64-68
// regardless of launch bounds -> structural scratch, not regalloc pressure).
// T=1 token/wave keeps peak live state ~60-70 regs. w_out from L2-hot global.

#define D 768
#define NF4 (D / 4)   // 192
#define NN 21
#define TPB 512       // 8 waves/block
#define NBLK 512      // 2 blocks/CU (LDS 63KB)
#define NWAVES (NBLK * (TPB / 64))  // 4096

__device__ __forceinline__ float gelu_exact(float v) {
  return 0.5f * v * (1.0f + erff(v * 0.70710678118654752440f));
}

template <int CTRL>
__device__ __forceinline__ float dppadd(float v) {
  int m = __builtin_amdgcn_update_dpp(0, __float_as_int(v), CTRL, 0xF, 0xF, true);
  return v + __int_as_float(m);
}

// Full 64-lane sum; result identical in every lane (branch decisions must be
// wave-uniform). 4 DPP steps (VALU pipe) + 2 shfl (LDS pipe).
__device__ __forceinline__ float wave_red(float v) {
  v = dppadd<0x140>(v);  // ROW_MIRROR
  v = dppadd<0x141>(v);  // ROW_HALF_MIRROR
  v = dppadd<0x4E>(v);   // QUAD_PERM [2,3,0,1] (xor 2)
  v = dppadd<0xB1>(v);   // QUAD_PERM [1,0,3,2] (xor 1)
  v += __shfl_xor(v, 16);
  v += __shfl_xor(v, 32);
  return v;
}

__device__ __forceinline__ float dot12(float4 a0, float4 a1, float4 a2,
                                       float4 w0, float4 w1, float4 w2) {
  float s = a0.x * w0.x;
  s = fmaf(a0.y, w0.y, s); s = fmaf(a0.z, w0.z, s); s = fmaf(a0.w, w0.w, s);
  s = fmaf(a1.x, w1.x, s); s = fmaf(a1.y, w1.y, s); s = fmaf(a1.z, w1.z, s);
  s = fmaf(a1.w, w1.w, s); s = fmaf(a2.x, w2.x, s); s = fmaf(a2.y, w2.y, s);
  s = fmaf(a2.z, w2.z, s); s = fmaf(a2.w, w2.w, s);
  return s;
}

// Accumulate g * wo[row] from GLOBAL (L2-hot 63KB table); row is wave-uniform.
__device__ __forceinline__ void accrow_g(const float* __restrict__ wo, int u,
                                         int lane, float g, float4& a0,
                                         float4& a1, float4& a2) {
  const float4* r =
      (const float4*)(wo + (size_t)__builtin_amdgcn_readfirstlane(u) * D);
  float4 w0 = r[lane], w1 = r[lane + 64], w2 = r[lane + 128];
  a0.x = fmaf(g, w0.x, a0.x); a0.y = fmaf(g, w0.y, a0.y);
  a0.z = fmaf(g, w0.z, a0.z); a0.w = fmaf(g, w0.w, a0.w);
  a1.x = fmaf(g, w1.x, a1.x); a1.y = fmaf(g, w1.y, a1.y);
  a1.z = fmaf(g, w1.z, a1.z); a1.w = fmaf(g, w1.w, a1.w);
  a2.x = fmaf(g, w2.x, a2.x); a2.y = fmaf(g, w2.y, a2.y);
  a2.z = fmaf(g, w2.z, a2.z); a2.w = fmaf(g, w2.w, a2.w);
}

// 21 wave-uniform logits (named) -> traversal via selects -> 5 weighted rows.
__device__ __forceinline__ void token_out(
    float n0, float n1, float n2, float n3, float n4, float n5, float n6,
    float n7, float n8, float n9, float n10, float n11, float n12, float n13,
    float n14, float n15, float n16, float n17, float n18, float n19,
    float n20, const float* __restrict__ wo, int lane,
    float* __restrict__ outp) {
  float l0 = n0;
  int b0 = l0 > 0.0f;
  float l1 = b0 ? n2 : n1;
  int b1 = l1 > 0.0f;
  float l2 = b0 ? (b1 ? n6 : n5) : (b1 ? n4 : n3);
  int b2 = l2 > 0.0f;
  float m0 = b2 ? n8 : n7;
  float m1 = b2 ? n10 : n9;
  float m2 = b2 ? n12 : n11;
  float m3 = b2 ? n14 : n13;
  float l3 = b0 ? (b1 ? m3 : m2) : (b1 ? m1 : m0);
  int b3 = l3 > 0.0f;
  int i4 = (b0 << 3) | (b1 << 2) | (b2 << 1) | b3;  // u4 = 15+min(i4,5)
  float l4 = n15;
  l4 = (i4 >= 1) ? n16 : l4;
  l4 = (i4 >= 2) ? n17 : l4;
  l4 = (i4 >= 3) ? n18 : l4;
  l4 = (i4 >= 4) ? n19 : l4;
  l4 = (i4 >= 5) ? n20 : l4;

  int u1 = 1 + b0;
  int u2 = 3 + 2 * b0 + b1;
  int u3 = 7 + 4 * b0 + 2 * b1 + b2;
  int u4 = 15 + (i4 < 5 ? i4 : 5);

  float g1 = gelu_exact(l0);
  float g2 = gelu_exact(l1);
  float g3 = gelu_exact(l2);
  float g4 = gelu_exact(l3);
  float g5 = gelu_exact(l4) + 5.0f * gelu_exact(n20);

  float4 a0 = {0.f, 0.f, 0.f, 0.f}, a1 = a0, a2 = a0;
  accrow_g(wo, u1, lane, g1, a0, a1, a2);
  accrow_g(wo, u2, lane, g2, a0, a1, a2);
  accrow_g(wo, u3, lane, g3, a0, a1, a2);
  accrow_g(wo, u4, lane, g4, a0, a1, a2);
  accrow_g(wo, NN - 1, lane, g5, a0, a1, a2);

  float4* op = (float4*)outp;
  op[lane] = a0;
  op[lane + 64] = a1;
  op[lane + 128] = a2;
}

#define FOR21(F)                                                        \
  F(0) F(1) F(2) F(3) F(4) F(5) F(6) F(7) F(8) F(9) F(10) F(11) F(12)  \
  F(13) F(14) F(15) F(16) F(17) F(18) F(19) F(20)

__global__ __launch_bounds__(TPB) void fff_kernel(
    const float* __restrict__ x, const float* __restrict__ wi,
    const float* __restrict__ wo, float* __restrict__ out, int ntok) {
  __shared__ __align__(16) float s_wi[NN * D];  // 63 KB -> 2 blocks/CU

  const int tid = threadIdx.x;
  {
    const float4* a = (const float4*)wi;
    float4* sa = (float4*)s_wi;
    for (int i = tid; i < NN * NF4; i += TPB) sa[i] = a[i];
  }
  __syncthreads();

  const int lane = tid & 63;
  const int wid = (blockIdx.x << 3) | (tid >> 6);
  const float4* swi4 = (const float4*)s_wi;

  for (int tok = wid; tok < ntok; tok += NWAVES) {
    const float4* xp = (const float4*)(x + (size_t)tok * D);
    float4 x0 = xp[lane], x1 = xp[lane + 64], x2 = xp[lane + 128];

    // 21 named scalar logits: dot (per-lane partial) + immediate wave reduce.
#define DECLR(n) float r##n;
    FOR21(DECLR)
#undef DECLR
#define DOTR(n)                                       \
  {                                                   \
    float4 w0 = swi4[(n) * NF4 + lane];               \
    float4 w1 = swi4[(n) * NF4 + lane + 64];          \
    float4 w2 = swi4[(n) * NF4 + lane + 128];         \
    r##n = dot12(x0, x1, x2, w0, w1, w2);             \
  }
    FOR21(DOTR)
#undef DOTR
#define REDR(n) r##n = wave_red(r##n);
    FOR21(REDR)
#undef REDR

    token_out(r0, r1, r2, r3, r4, r5, r6, r7, r8, r9, r10, r11, r12, r13,
              r14, r15, r16, r17, r18, r19, r20, wo, lane,
              out + (size_t)tok * D);
  }
}

extern "C" void kernel_launch(void* const* d_in, const int* in_sizes, int n_in,
                              void* d_out, int out_size, void* d_ws,
                              size_t ws_size, hipStream_t stream) {
  const float* x = (const float*)d_in[0];
  const float* wi = (const float*)d_in[1];
  const float* wo = (const float*)d_in[2];
  float* out = (float*)d_out;
  const int ntok = in_sizes[0] / D;  // 16384
  fff_kernel<<<NBLK, TPB, 0, stream>>>(x, wi, wo, out, ntok);
}